// Round 4
// baseline (386.692 us; speedup 1.0000x reference)
//
#include <hip/hip_runtime.h>

typedef short s8v __attribute__((ext_vector_type(8)));
typedef float f4v __attribute__((ext_vector_type(4)));

#define NN 8192
#define KN 32
#define DD 128
#define HH 256

static __device__ __forceinline__ unsigned short f2bf(float f) {
    union { float f; unsigned u; } v; v.f = f;
    unsigned r = v.u + 0x7fffu + ((v.u >> 16) & 1u);
    return (unsigned short)(r >> 16);
}
static __device__ __forceinline__ float bf2f(unsigned short h) {
    union { unsigned u; float f; } v; v.u = ((unsigned)h) << 16;
    return v.f;
}

// ---------------------------------------------------------------------------
// Kernel 0: weight prep.
//  W1cat (128 x 512): Wcat[k][n] = n<256 ? W1[k][n] : W1[128+k][n-256]
//  stored hi/lo bf16 in MFMA-B layout: idx = ((k/32)*512 + n)*32 + (k%32)
//  W2s: bf16, idx = ((k/32)*256 + n)*32 + (k%32)
// ---------------------------------------------------------------------------
__global__ __launch_bounds__(256) void prep_kernel(
    const float* __restrict__ W1, const float* __restrict__ W2,
    unsigned short* __restrict__ W1sh, unsigned short* __restrict__ W1sl,
    unsigned short* __restrict__ W2s)
{
    int tid = blockIdx.x * 256 + threadIdx.x;          // 0..131071
    if (tid < 128 * 512) {
        int k = tid >> 9;                              // 0..127
        int n = tid & 511;                             // 0..511
        float w = (n < 256) ? W1[k * 256 + n] : W1[(128 + k) * 256 + (n - 256)];
        unsigned short hi = f2bf(w);
        float lo = w - bf2f(hi);
        int idx = ((k >> 5) * 512 + n) * 32 + (k & 31);
        W1sh[idx] = hi;
        W1sl[idx] = f2bf(lo);
    } else {
        int t2 = tid - 128 * 512;                      // 0..65535
        int k = t2 >> 8;                               // 0..255
        int n = t2 & 255;
        W2s[((k >> 5) * 256 + n) * 32 + (k & 31)] = f2bf(W2[k * 256 + n]);
    }
}

// ---------------------------------------------------------------------------
// Kernel 1: PQ = x @ W1cat  (hi/lo split bf16 MFMA ~= fp32 accuracy).
//  P (fp32, +b1) = cols 0..255 ; Q (bf16) = cols 256..511.
//  block: M=64 rows, N=256 cols, K=128. 4 waves split N (64 each).
// ---------------------------------------------------------------------------
__global__ __launch_bounds__(256) void pq_kernel(
    const float* __restrict__ x, const unsigned short* __restrict__ W1sh,
    const unsigned short* __restrict__ W1sl, const float* __restrict__ b1,
    float* __restrict__ P, unsigned short* __restrict__ Q)
{
    __shared__ unsigned short Ah[64 * 136];   // [m][k], pad 128->136 shorts
    __shared__ unsigned short Al[64 * 136];
    int t  = threadIdx.x;
    int r0 = blockIdx.x * 64;
    int n0 = blockIdx.y * 256;

    // --- build A (x rows) as hi/lo bf16 in LDS ---
    {
        int m   = (t & 15) | ((t >> 6) << 4);          // 0..63, lane-unique within wave
        int seg = (t >> 4) & 3;
        const float* xr = x + (r0 + m) * DD + seg * 32;
        #pragma unroll
        for (int it = 0; it < 4; ++it) {
            f4v v0 = *(const f4v*)(xr + it * 8);
            f4v v1 = *(const f4v*)(xr + it * 8 + 4);
            s8v hh, ll;
            #pragma unroll
            for (int e = 0; e < 8; ++e) {
                float v = (e < 4) ? v0[e] : v1[e - 4];
                unsigned short hi = f2bf(v);
                hh[e] = (short)hi;
                ll[e] = (short)f2bf(v - bf2f(hi));
            }
            int c = seg * 32 + it * 8;
            *(s8v*)(Ah + m * 136 + c) = hh;
            *(s8v*)(Al + m * 136 + c) = ll;
        }
    }
    __syncthreads();

    int lane = t & 63, wn = t >> 6, l15 = lane & 15, q = lane >> 4;
    f4v acc[4][4];
    #pragma unroll
    for (int mt = 0; mt < 4; ++mt)
        #pragma unroll
        for (int nt = 0; nt < 4; ++nt) acc[mt][nt] = (f4v){0.f, 0.f, 0.f, 0.f};

    #pragma unroll
    for (int kt = 0; kt < 4; ++kt) {
        s8v ah[4], al[4], bh[4], bl[4];
        #pragma unroll
        for (int mt = 0; mt < 4; ++mt) {
            int m = mt * 16 + l15;
            ah[mt] = *(const s8v*)(Ah + m * 136 + kt * 32 + q * 8);
            al[mt] = *(const s8v*)(Al + m * 136 + kt * 32 + q * 8);
        }
        #pragma unroll
        for (int nt = 0; nt < 4; ++nt) {
            int n = n0 + wn * 64 + nt * 16 + l15;      // global col 0..511
            int idx = (kt * 512 + n) * 32 + q * 8;
            bh[nt] = *(const s8v*)(W1sh + idx);
            bl[nt] = *(const s8v*)(W1sl + idx);
        }
        #pragma unroll
        for (int mt = 0; mt < 4; ++mt)
            #pragma unroll
            for (int nt = 0; nt < 4; ++nt) {
                acc[mt][nt] = __builtin_amdgcn_mfma_f32_16x16x32_bf16(ah[mt], bh[nt], acc[mt][nt], 0, 0, 0);
                acc[mt][nt] = __builtin_amdgcn_mfma_f32_16x16x32_bf16(ah[mt], bl[nt], acc[mt][nt], 0, 0, 0);
                acc[mt][nt] = __builtin_amdgcn_mfma_f32_16x16x32_bf16(al[mt], bh[nt], acc[mt][nt], 0, 0, 0);
            }
    }

    // --- epilogue: cols<256 -> P (fp32 + b1), cols>=256 -> Q (bf16) ---
    #pragma unroll
    for (int nt = 0; nt < 4; ++nt) {
        int cg = n0 + wn * 64 + nt * 16 + l15;
        if (cg < 256) {
            float bias = b1[cg];
            #pragma unroll
            for (int mt = 0; mt < 4; ++mt)
                #pragma unroll
                for (int r = 0; r < 4; ++r) {
                    int row = r0 + mt * 16 + q * 4 + r;
                    P[row * 256 + cg] = acc[mt][nt][r] + bias;
                }
        } else {
            int cq = cg - 256;
            #pragma unroll
            for (int mt = 0; mt < 4; ++mt)
                #pragma unroll
                for (int r = 0; r < 4; ++r) {
                    int row = r0 + mt * 16 + q * 4 + r;
                    Q[row * 256 + cq] = f2bf(acc[mt][nt][r]);
                }
        }
    }
}

// ---------------------------------------------------------------------------
// Kernel 2: fused main. One block = 2 nodes (M = 64 rows of h1).
//  r1 compute bodies (scalar converts), plus:
//  - cur == g (nbrs[:,0] is arange by construction): no pointer-chase.
//  - direct NT zero-stores for both output rows, issued just before the
//    phase-3 barrier (which already drains vmcnt) -> no LDS image, no
//    extra barriers, store drain overlaps nothing on the load path.
//  - inline scatter in phase 4 from registers (no wbuf round-trip).
// ---------------------------------------------------------------------------
__global__ __launch_bounds__(256) void main_kernel(
    const float* __restrict__ P, const unsigned short* __restrict__ Q,
    const unsigned short* __restrict__ W2s,
    const float* __restrict__ b2, const float* __restrict__ W3,
    const int* __restrict__ nbrs, const float* __restrict__ t_arr,
    const float* __restrict__ e_hat, const float* __restrict__ b3p,
    const float* __restrict__ bscal, float* __restrict__ out)
{
    __shared__ unsigned short A[64 * 264];   // h1 bf16, [m][k], pad 256->264
    __shared__ float mlpbuf[64][4];          // per-row partial mlp by wave
    int t = threadIdx.x;
    int node0 = blockIdx.x * 2;
    float* PW = out + NN;                    // pairwise base

    // --- phase 1: build h1 = bf16(relu(P[g] + Q[j])) into LDS ---
    {
        int m   = (t & 15) | ((t >> 6) << 4);     // 0..63
        int seg = (t >> 4) & 3;
        int g = node0 + (m >> 5);
        int j = nbrs[g * 33 + 1 + (m & 31)];
        const float* Pr = P + g * 256 + seg * 64;     // cur == g
        const unsigned short* Qr = Q + j * 256 + seg * 64;
        #pragma unroll
        for (int it = 0; it < 8; ++it) {
            f4v p0 = *(const f4v*)(Pr + it * 8);
            f4v p1 = *(const f4v*)(Pr + it * 8 + 4);
            s8v qv = *(const s8v*)(Qr + it * 8);
            s8v hv;
            #pragma unroll
            for (int e = 0; e < 8; ++e) {
                float pv = (e < 4) ? p0[e] : p1[e - 4];
                float v = pv + bf2f((unsigned short)qv[e]);
                v = v > 0.f ? v : 0.f;
                hv[e] = (short)f2bf(v);
            }
            *(s8v*)(A + m * 264 + seg * 64 + it * 8) = hv;
        }
    }
    __syncthreads();

    // --- phase 2: K-loop, no barriers. B direct from L2. ---
    int lane = t & 63, wn = t >> 6, l15 = lane & 15, q = lane >> 4;
    f4v acc[4][4];
    #pragma unroll
    for (int mt = 0; mt < 4; ++mt)
        #pragma unroll
        for (int nt = 0; nt < 4; ++nt) acc[mt][nt] = (f4v){0.f, 0.f, 0.f, 0.f};

    #pragma unroll
    for (int kt = 0; kt < 8; ++kt) {
        s8v a[4], b[4];
        #pragma unroll
        for (int mt = 0; mt < 4; ++mt)
            a[mt] = *(const s8v*)(A + (mt * 16 + l15) * 264 + kt * 32 + q * 8);
        #pragma unroll
        for (int nt = 0; nt < 4; ++nt) {
            int n = wn * 64 + nt * 16 + l15;
            b[nt] = *(const s8v*)(W2s + (kt * 256 + n) * 32 + q * 8);
        }
        #pragma unroll
        for (int mt = 0; mt < 4; ++mt)
            #pragma unroll
            for (int nt = 0; nt < 4; ++nt)
                acc[mt][nt] = __builtin_amdgcn_mfma_f32_16x16x32_bf16(a[mt], b[nt], acc[mt][nt], 0, 0, 0);
    }

    // --- phase 3: mlp partials = sum_c relu(h2+b2)*W3 over this wave's cols ---
    float p[4][4];
    #pragma unroll
    for (int mt = 0; mt < 4; ++mt)
        #pragma unroll
        for (int r = 0; r < 4; ++r) p[mt][r] = 0.f;
    #pragma unroll
    for (int nt = 0; nt < 4; ++nt) {
        int c = wn * 64 + nt * 16 + l15;
        float bb = b2[c], w3 = W3[c];
        #pragma unroll
        for (int mt = 0; mt < 4; ++mt)
            #pragma unroll
            for (int r = 0; r < 4; ++r) {
                float v = acc[mt][nt][r] + bb;
                v = v > 0.f ? v : 0.f;
                p[mt][r] += v * w3;
            }
    }
    #pragma unroll
    for (int off = 1; off < 16; off <<= 1)
        #pragma unroll
        for (int mt = 0; mt < 4; ++mt)
            #pragma unroll
            for (int r = 0; r < 4; ++r)
                p[mt][r] += __shfl_xor(p[mt][r], off, 64);
    if (l15 == 0) {
        #pragma unroll
        for (int mt = 0; mt < 4; ++mt)
            #pragma unroll
            for (int r = 0; r < 4; ++r)
                mlpbuf[mt * 16 + q * 4 + r][wn] = p[mt][r];
    }

    // --- zero both output rows (contiguous 64KB) with NT stores; the
    //     barrier below drains them (compiler emits vmcnt(0) at barriers) ---
    {
        float* dst = PW + (long)node0 * NN;   // rows node0, node0+1 contiguous
        f4v z = (f4v){0.f, 0.f, 0.f, 0.f};
        #pragma unroll
        for (int i = 0; i < 16; ++i)
            __builtin_nontemporal_store(z, (f4v*)(dst + t * 4 + i * 1024));
    }
    __syncthreads();   // mlpbuf visible + all zero-stores drained

    // --- phase 4: per-node softmax, Y_pred, direct scatter ---
    if (t < 128) {
        int node = t >> 6;
        int k = t & 63;
        if (k < 32) {
            int g = node0 + node;
            int m = node * 32 + k;
            float mlp = mlpbuf[m][0] + mlpbuf[m][1] + mlpbuf[m][2] + mlpbuf[m][3] + b3p[0];
            float aabs = bscal[0] * fabsf(mlp);
            float amax = aabs;
            #pragma unroll
            for (int off = 1; off < 32; off <<= 1)
                amax = fmaxf(amax, __shfl_xor(amax, off, 64));
            float e = __expf(aabs - amax);
            float s = e;
            #pragma unroll
            for (int off = 1; off < 32; off <<= 1)
                s += __shfl_xor(s, off, 64);
            float w = mlp * (e / s);

            int j = nbrs[g * 33 + 1 + k];
            float prop = t_arr[j] - e_hat[j];
            float yp = prop * w;
            #pragma unroll
            for (int off = 1; off < 32; off <<= 1)
                yp += __shfl_xor(yp, off, 64);
            if (k == 0) out[g] = yp;

            // numpy last-write-wins dedup; skip diagonal (cur == g)
            bool write = (j != g);
            for (int kk = 0; kk < 32; ++kk) {
                int jv = __shfl(j, kk, 64);
                if (kk > k && jv == j) write = false;
            }
            if (write) PW[(long)g * NN + j] = w;
        }
    }
}

// ---------------------------------------------------------------------------
extern "C" void kernel_launch(void* const* d_in, const int* in_sizes, int n_in,
                              void* d_out, int out_size, void* d_ws, size_t ws_size,
                              hipStream_t stream) {
    const float* x     = (const float*)d_in[0];
    const int*   nbrs  = (const int*)d_in[1];
    const float* t     = (const float*)d_in[2];
    const float* e_hat = (const float*)d_in[3];
    const float* W1    = (const float*)d_in[4];
    const float* b1    = (const float*)d_in[5];
    const float* W2    = (const float*)d_in[6];
    const float* b2    = (const float*)d_in[7];
    const float* W3    = (const float*)d_in[8];
    const float* b3    = (const float*)d_in[9];
    const float* b     = (const float*)d_in[10];

    char* ws = (char*)d_ws;
    float*          P     = (float*)ws;                              // 8 MB
    unsigned short* Q     = (unsigned short*)(ws + 8388608);         // 4 MB
    unsigned short* W1sh  = (unsigned short*)(ws + 12582912);        // 128 KB
    unsigned short* W1sl  = (unsigned short*)(ws + 12713984);        // 128 KB
    unsigned short* W2s   = (unsigned short*)(ws + 12845056);        // 128 KB

    prep_kernel<<<512, 256, 0, stream>>>(W1, W2, W1sh, W1sl, W2s);
    pq_kernel<<<dim3(128, 2), 256, 0, stream>>>(x, W1sh, W1sl, b1, P, Q);
    main_kernel<<<4096, 256, 0, stream>>>(P, Q, W2s, b2, W3, nbrs, t, e_hat,
                                          b3, b, (float*)d_out);
}

// Round 5
// 353.466 us; speedup vs baseline: 1.0940x; 1.0940x over previous
//
#include <hip/hip_runtime.h>

typedef short s8v __attribute__((ext_vector_type(8)));
typedef float f4v __attribute__((ext_vector_type(4)));

#define NN 8192
#define KN 32
#define DD 128
#define HH 256

static __device__ __forceinline__ unsigned short f2bf(float f) {
    union { float f; unsigned u; } v; v.f = f;
    unsigned r = v.u + 0x7fffu + ((v.u >> 16) & 1u);
    return (unsigned short)(r >> 16);
}
static __device__ __forceinline__ float bf2f(unsigned short h) {
    union { unsigned u; float f; } v; v.u = ((unsigned)h) << 16;
    return v.f;
}

// ---------------------------------------------------------------------------
// Kernel 0: weight prep.
//  W1cat (128 x 512): Wcat[k][n] = n<256 ? W1[k][n] : W1[128+k][n-256]
//  stored hi/lo bf16 in MFMA-B layout: idx = ((k/32)*512 + n)*32 + (k%32)
//  W2s: bf16, idx = ((k/32)*256 + n)*32 + (k%32)
// ---------------------------------------------------------------------------
__global__ __launch_bounds__(256) void prep_kernel(
    const float* __restrict__ W1, const float* __restrict__ W2,
    unsigned short* __restrict__ W1sh, unsigned short* __restrict__ W1sl,
    unsigned short* __restrict__ W2s)
{
    int tid = blockIdx.x * 256 + threadIdx.x;          // 0..131071
    if (tid < 128 * 512) {
        int k = tid >> 9;                              // 0..127
        int n = tid & 511;                             // 0..511
        float w = (n < 256) ? W1[k * 256 + n] : W1[(128 + k) * 256 + (n - 256)];
        unsigned short hi = f2bf(w);
        float lo = w - bf2f(hi);
        int idx = ((k >> 5) * 512 + n) * 32 + (k & 31);
        W1sh[idx] = hi;
        W1sl[idx] = f2bf(lo);
    } else {
        int t2 = tid - 128 * 512;                      // 0..65535
        int k = t2 >> 8;                               // 0..255
        int n = t2 & 255;
        W2s[((k >> 5) * 256 + n) * 32 + (k & 31)] = f2bf(W2[k * 256 + n]);
    }
}

// ---------------------------------------------------------------------------
// Kernel 1: PQ = x @ W1cat  (hi/lo split bf16 MFMA ~= fp32 accuracy).
//  P (fp32, +b1) = cols 0..255 ; Q (bf16) = cols 256..511.
//  block: M=64 rows, N=256 cols, K=128. 4 waves split N (64 each).
// ---------------------------------------------------------------------------
__global__ __launch_bounds__(256) void pq_kernel(
    const float* __restrict__ x, const unsigned short* __restrict__ W1sh,
    const unsigned short* __restrict__ W1sl, const float* __restrict__ b1,
    float* __restrict__ P, unsigned short* __restrict__ Q)
{
    __shared__ unsigned short Ah[64 * 136];   // [m][k], pad 128->136 shorts
    __shared__ unsigned short Al[64 * 136];
    int t  = threadIdx.x;
    int r0 = blockIdx.x * 64;
    int n0 = blockIdx.y * 256;

    // --- build A (x rows) as hi/lo bf16 in LDS ---
    {
        int m   = (t & 15) | ((t >> 6) << 4);          // 0..63, lane-unique within wave
        int seg = (t >> 4) & 3;
        const float* xr = x + (r0 + m) * DD + seg * 32;
        #pragma unroll
        for (int it = 0; it < 4; ++it) {
            f4v v0 = *(const f4v*)(xr + it * 8);
            f4v v1 = *(const f4v*)(xr + it * 8 + 4);
            s8v hh, ll;
            #pragma unroll
            for (int e = 0; e < 8; ++e) {
                float v = (e < 4) ? v0[e] : v1[e - 4];
                unsigned short hi = f2bf(v);
                hh[e] = (short)hi;
                ll[e] = (short)f2bf(v - bf2f(hi));
            }
            int c = seg * 32 + it * 8;
            *(s8v*)(Ah + m * 136 + c) = hh;
            *(s8v*)(Al + m * 136 + c) = ll;
        }
    }
    __syncthreads();

    int lane = t & 63, wn = t >> 6, l15 = lane & 15, q = lane >> 4;
    f4v acc[4][4];
    #pragma unroll
    for (int mt = 0; mt < 4; ++mt)
        #pragma unroll
        for (int nt = 0; nt < 4; ++nt) acc[mt][nt] = (f4v){0.f, 0.f, 0.f, 0.f};

    #pragma unroll
    for (int kt = 0; kt < 4; ++kt) {
        s8v ah[4], al[4], bh[4], bl[4];
        #pragma unroll
        for (int mt = 0; mt < 4; ++mt) {
            int m = mt * 16 + l15;
            ah[mt] = *(const s8v*)(Ah + m * 136 + kt * 32 + q * 8);
            al[mt] = *(const s8v*)(Al + m * 136 + kt * 32 + q * 8);
        }
        #pragma unroll
        for (int nt = 0; nt < 4; ++nt) {
            int n = n0 + wn * 64 + nt * 16 + l15;      // global col 0..511
            int idx = (kt * 512 + n) * 32 + q * 8;
            bh[nt] = *(const s8v*)(W1sh + idx);
            bl[nt] = *(const s8v*)(W1sl + idx);
        }
        #pragma unroll
        for (int mt = 0; mt < 4; ++mt)
            #pragma unroll
            for (int nt = 0; nt < 4; ++nt) {
                acc[mt][nt] = __builtin_amdgcn_mfma_f32_16x16x32_bf16(ah[mt], bh[nt], acc[mt][nt], 0, 0, 0);
                acc[mt][nt] = __builtin_amdgcn_mfma_f32_16x16x32_bf16(ah[mt], bl[nt], acc[mt][nt], 0, 0, 0);
                acc[mt][nt] = __builtin_amdgcn_mfma_f32_16x16x32_bf16(al[mt], bh[nt], acc[mt][nt], 0, 0, 0);
            }
    }

    // --- epilogue: cols<256 -> P (fp32 + b1), cols>=256 -> Q (bf16) ---
    #pragma unroll
    for (int nt = 0; nt < 4; ++nt) {
        int cg = n0 + wn * 64 + nt * 16 + l15;
        if (cg < 256) {
            float bias = b1[cg];
            #pragma unroll
            for (int mt = 0; mt < 4; ++mt)
                #pragma unroll
                for (int r = 0; r < 4; ++r) {
                    int row = r0 + mt * 16 + q * 4 + r;
                    P[row * 256 + cg] = acc[mt][nt][r] + bias;
                }
        } else {
            int cq = cg - 256;
            #pragma unroll
            for (int mt = 0; mt < 4; ++mt)
                #pragma unroll
                for (int r = 0; r < 4; ++r) {
                    int row = r0 + mt * 16 + q * 4 + r;
                    Q[row * 256 + cq] = f2bf(acc[mt][nt][r]);
                }
        }
    }
}

// ---------------------------------------------------------------------------
// Kernel 2: fused main. One block = 2 nodes (M = 64 rows of h1).
//  r1 base (353 us) with only attribution-clean deltas:
//  - cur == g (nbrs[:,0] is arange by construction): no pointer-chase.
//  - phase 1: stage 12 loads/half in regs, SCALAR converts (no asm packing).
//  - image zero runs on waves 2-3 during phase-4 softmax; row-0 stream
//    rezeroes in-place for row 1 (one zero pass + one barrier saved).
//  - write path (LDS image + wbuf + full-line NT stream at kernel end)
//    byte-identical to r1: keeps the fill at ~168 us.
// ---------------------------------------------------------------------------
__global__ __launch_bounds__(256) void main_kernel(
    const float* __restrict__ P, const unsigned short* __restrict__ Q,
    const unsigned short* __restrict__ W2s,
    const float* __restrict__ b2, const float* __restrict__ W3,
    const int* __restrict__ nbrs, const float* __restrict__ t_arr,
    const float* __restrict__ e_hat, const float* __restrict__ b3p,
    const float* __restrict__ bscal, float* __restrict__ out)
{
    __shared__ unsigned short A[64 * 264];   // h1 bf16 [m][k] pad 256->264; reused as 32KB row image
    __shared__ float mlpbuf[64][4];          // per-row partial mlp by wave
    __shared__ float wbuf_w[2][32];          // per-node scatter values
    __shared__ int   wbuf_j[2][32];          // per-node scatter columns (-1 = skip)
    int t = threadIdx.x;
    int node0 = blockIdx.x * 2;
    float* PW = out + NN;                    // pairwise base

    // --- phase 1: build h1 = bf16(relu(P[g] + Q[j])) into LDS ---
    {
        int m   = (t & 15) | ((t >> 6) << 4);     // 0..63
        int seg = (t >> 4) & 3;
        int g = node0 + (m >> 5);
        int j = nbrs[g * 33 + 1 + (m & 31)];      // only dependent load left
        const float* Pr = P + g * 256 + seg * 64; // cur == g: pure arithmetic
        const unsigned short* Qr = Q + j * 256 + seg * 64;

        #pragma unroll
        for (int half = 0; half < 2; ++half) {
            // stage 12 independent loads, then convert (scalar f2bf, as r1)
            f4v p0[4], p1[4];
            s8v qv[4];
            #pragma unroll
            for (int it = 0; it < 4; ++it) {
                int itg = half * 4 + it;
                p0[it] = *(const f4v*)(Pr + itg * 8);
                p1[it] = *(const f4v*)(Pr + itg * 8 + 4);
                qv[it] = *(const s8v*)(Qr + itg * 8);
            }
            #pragma unroll
            for (int it = 0; it < 4; ++it) {
                int itg = half * 4 + it;
                s8v hv;
                #pragma unroll
                for (int e = 0; e < 8; ++e) {
                    float pv = (e < 4) ? p0[it][e] : p1[it][e - 4];
                    float v = pv + bf2f((unsigned short)qv[it][e]);
                    v = v > 0.f ? v : 0.f;
                    hv[e] = (short)f2bf(v);
                }
                *(s8v*)(A + m * 264 + seg * 64 + itg * 8) = hv;
            }
        }
    }
    __syncthreads();

    // --- phase 2: K-loop, no barriers. B direct from L2. ---
    int lane = t & 63, wn = t >> 6, l15 = lane & 15, q = lane >> 4;
    f4v acc[4][4];
    #pragma unroll
    for (int mt = 0; mt < 4; ++mt)
        #pragma unroll
        for (int nt = 0; nt < 4; ++nt) acc[mt][nt] = (f4v){0.f, 0.f, 0.f, 0.f};

    #pragma unroll
    for (int kt = 0; kt < 8; ++kt) {
        s8v a[4], b[4];
        #pragma unroll
        for (int mt = 0; mt < 4; ++mt)
            a[mt] = *(const s8v*)(A + (mt * 16 + l15) * 264 + kt * 32 + q * 8);
        #pragma unroll
        for (int nt = 0; nt < 4; ++nt) {
            int n = wn * 64 + nt * 16 + l15;
            b[nt] = *(const s8v*)(W2s + (kt * 256 + n) * 32 + q * 8);
        }
        #pragma unroll
        for (int mt = 0; mt < 4; ++mt)
            #pragma unroll
            for (int nt = 0; nt < 4; ++nt)
                acc[mt][nt] = __builtin_amdgcn_mfma_f32_16x16x32_bf16(a[mt], b[nt], acc[mt][nt], 0, 0, 0);
    }

    // --- phase 3: mlp partials = sum_c relu(h2+b2)*W3 over this wave's cols ---
    float p[4][4];
    #pragma unroll
    for (int mt = 0; mt < 4; ++mt)
        #pragma unroll
        for (int r = 0; r < 4; ++r) p[mt][r] = 0.f;
    #pragma unroll
    for (int nt = 0; nt < 4; ++nt) {
        int c = wn * 64 + nt * 16 + l15;
        float bb = b2[c], w3 = W3[c];
        #pragma unroll
        for (int mt = 0; mt < 4; ++mt)
            #pragma unroll
            for (int r = 0; r < 4; ++r) {
                float v = acc[mt][nt][r] + bb;
                v = v > 0.f ? v : 0.f;
                p[mt][r] += v * w3;
            }
    }
    #pragma unroll
    for (int off = 1; off < 16; off <<= 1)
        #pragma unroll
        for (int mt = 0; mt < 4; ++mt)
            #pragma unroll
            for (int r = 0; r < 4; ++r)
                p[mt][r] += __shfl_xor(p[mt][r], off, 64);
    if (l15 == 0) {
        #pragma unroll
        for (int mt = 0; mt < 4; ++mt)
            #pragma unroll
            for (int r = 0; r < 4; ++r)
                mlpbuf[mt * 16 + q * 4 + r][wn] = p[mt][r];
    }
    __syncthreads();   // mlpbuf ready; A free (K-loop LDS reads all complete)

    // --- phase 4 (waves 0-1): softmax, Y_pred, scatter list
    //     (waves 2-3): zero the 32KB row image in parallel ---
    float* img = (float*)A;
    if (t < 128) {
        int node = t >> 6;
        int k = t & 63;
        if (k < 32) {
            int g = node0 + node;
            int m = node * 32 + k;
            float mlp = mlpbuf[m][0] + mlpbuf[m][1] + mlpbuf[m][2] + mlpbuf[m][3] + b3p[0];
            float aabs = bscal[0] * fabsf(mlp);
            float amax = aabs;
            #pragma unroll
            for (int off = 1; off < 32; off <<= 1)
                amax = fmaxf(amax, __shfl_xor(amax, off, 64));
            float e = __expf(aabs - amax);
            float s = e;
            #pragma unroll
            for (int off = 1; off < 32; off <<= 1)
                s += __shfl_xor(s, off, 64);
            float w = mlp * (e / s);

            int j = nbrs[g * 33 + 1 + k];
            float prop = t_arr[j] - e_hat[j];
            float yp = prop * w;
            #pragma unroll
            for (int off = 1; off < 32; off <<= 1)
                yp += __shfl_xor(yp, off, 64);
            if (k == 0) out[g] = yp;

            // numpy last-write-wins dedup; skip diagonal (cur == g)
            bool write = (j != g);
            for (int kk = 0; kk < 32; ++kk) {
                int jv = __shfl(j, kk, 64);
                if (kk > k && jv == j) write = false;
            }
            wbuf_w[node][k] = w;
            wbuf_j[node][k] = write ? j : -1;
        }
    } else {
        int tt = t - 128;                     // 0..127, 64 floats each
        f4v z = (f4v){0.f, 0.f, 0.f, 0.f};
        #pragma unroll
        for (int i = 0; i < 16; ++i)
            *(f4v*)(img + tt * 4 + i * 512) = z;
    }
    __syncthreads();                          // wbuf + zeros visible

    // --- phase 5: stream row 0 (rezeroing image for row 1), then row 1 ---
    if (t < 32) {
        int j = wbuf_j[0][t];
        if (j >= 0) img[j] = wbuf_w[0][t];
    }
    __syncthreads();
    {
        float* dst = PW + (long)node0 * NN;   // cur == node0
        f4v z = (f4v){0.f, 0.f, 0.f, 0.f};
        #pragma unroll
        for (int i = 0; i < 8; ++i) {
            f4v v = *(const f4v*)(img + t * 4 + i * 1024);
            *(f4v*)(img + t * 4 + i * 1024) = z;   // same-thread rezero (wave-ordered)
            __builtin_nontemporal_store(v, (f4v*)(dst + t * 4 + i * 1024));
        }
    }
    __syncthreads();
    if (t < 32) {
        int j = wbuf_j[1][t];
        if (j >= 0) img[j] = wbuf_w[1][t];
    }
    __syncthreads();
    {
        float* dst = PW + (long)(node0 + 1) * NN;
        #pragma unroll
        for (int i = 0; i < 8; ++i) {
            f4v v = *(const f4v*)(img + t * 4 + i * 1024);
            __builtin_nontemporal_store(v, (f4v*)(dst + t * 4 + i * 1024));
        }
    }
}

// ---------------------------------------------------------------------------
extern "C" void kernel_launch(void* const* d_in, const int* in_sizes, int n_in,
                              void* d_out, int out_size, void* d_ws, size_t ws_size,
                              hipStream_t stream) {
    const float* x     = (const float*)d_in[0];
    const int*   nbrs  = (const int*)d_in[1];
    const float* t     = (const float*)d_in[2];
    const float* e_hat = (const float*)d_in[3];
    const float* W1    = (const float*)d_in[4];
    const float* b1    = (const float*)d_in[5];
    const float* W2    = (const float*)d_in[6];
    const float* b2    = (const float*)d_in[7];
    const float* W3    = (const float*)d_in[8];
    const float* b3    = (const float*)d_in[9];
    const float* b     = (const float*)d_in[10];

    char* ws = (char*)d_ws;
    float*          P     = (float*)ws;                              // 8 MB
    unsigned short* Q     = (unsigned short*)(ws + 8388608);         // 4 MB
    unsigned short* W1sh  = (unsigned short*)(ws + 12582912);        // 128 KB
    unsigned short* W1sl  = (unsigned short*)(ws + 12713984);        // 128 KB
    unsigned short* W2s   = (unsigned short*)(ws + 12845056);        // 128 KB

    prep_kernel<<<512, 256, 0, stream>>>(W1, W2, W1sh, W1sl, W2s);
    pq_kernel<<<dim3(128, 2), 256, 0, stream>>>(x, W1sh, W1sl, b1, P, Q);
    main_kernel<<<4096, 256, 0, stream>>>(P, Q, W2s, b2, W3, nbrs, t, e_hat,
                                          b3, b, (float*)d_out);
}

// Round 6
// 351.322 us; speedup vs baseline: 1.1007x; 1.0061x over previous
//
#include <hip/hip_runtime.h>
#include <hip/hip_bf16.h>

typedef short s8v __attribute__((ext_vector_type(8)));
typedef float f4v __attribute__((ext_vector_type(4)));
typedef float f2v __attribute__((ext_vector_type(2)));
typedef unsigned u4v __attribute__((ext_vector_type(4)));

#define NN 8192
#define KN 32
#define DD 128
#define HH 256

static __device__ __forceinline__ unsigned short f2bf(float f) {
    union { float f; unsigned u; } v; v.f = f;
    unsigned r = v.u + 0x7fffu + ((v.u >> 16) & 1u);
    return (unsigned short)(r >> 16);
}
static __device__ __forceinline__ float bf2f(unsigned short h) {
    union { unsigned u; float f; } v; v.u = ((unsigned)h) << 16;
    return v.f;
}
// pack 2 fp32 -> dword of 2 bf16, RNE (same rounding as f2bf); compiler
// schedules this (no inline asm -- m240 lesson).
static __device__ __forceinline__ unsigned cvt2(float a, float b) {
    float2 f2; f2.x = a; f2.y = b;
    __hip_bfloat162 h = __float22bfloat162_rn(f2);
    union { __hip_bfloat162 h; unsigned u; } c; c.h = h;
    return c.u;
}
// unpack dword of 2 bf16 -> f2v
static __device__ __forceinline__ f2v unpk2(unsigned qd) {
    union { unsigned u; float f; } lo, hi;
    lo.u = qd << 16; hi.u = qd & 0xffff0000u;
    f2v r; r[0] = lo.f; r[1] = hi.f; return r;
}

// ---------------------------------------------------------------------------
// Kernel 0: weight prep.
//  W1cat (128 x 512): Wcat[k][n] = n<256 ? W1[k][n] : W1[128+k][n-256]
//  stored hi/lo bf16 in MFMA-B layout: idx = ((k/32)*512 + n)*32 + (k%32)
//  W2s: bf16, idx = ((k/32)*256 + n)*32 + (k%32)
// ---------------------------------------------------------------------------
__global__ __launch_bounds__(256) void prep_kernel(
    const float* __restrict__ W1, const float* __restrict__ W2,
    unsigned short* __restrict__ W1sh, unsigned short* __restrict__ W1sl,
    unsigned short* __restrict__ W2s)
{
    int tid = blockIdx.x * 256 + threadIdx.x;          // 0..131071
    if (tid < 128 * 512) {
        int k = tid >> 9;                              // 0..127
        int n = tid & 511;                             // 0..511
        float w = (n < 256) ? W1[k * 256 + n] : W1[(128 + k) * 256 + (n - 256)];
        unsigned short hi = f2bf(w);
        float lo = w - bf2f(hi);
        int idx = ((k >> 5) * 512 + n) * 32 + (k & 31);
        W1sh[idx] = hi;
        W1sl[idx] = f2bf(lo);
    } else {
        int t2 = tid - 128 * 512;                      // 0..65535
        int k = t2 >> 8;                               // 0..255
        int n = t2 & 255;
        W2s[((k >> 5) * 256 + n) * 32 + (k & 31)] = f2bf(W2[k * 256 + n]);
    }
}

// ---------------------------------------------------------------------------
// Kernel 1: PQ = x @ W1cat  (hi/lo split bf16 MFMA ~= fp32 accuracy).
//  P (fp32, +b1) = cols 0..255 ; Q (bf16) = cols 256..511.
//  block: M=64 rows, N=256 cols, K=128. 4 waves split N (64 each).
//  hi/lo build uses packed f2v math + pairwise cvt (compiler-scheduled).
// ---------------------------------------------------------------------------
__global__ __launch_bounds__(256) void pq_kernel(
    const float* __restrict__ x, const unsigned short* __restrict__ W1sh,
    const unsigned short* __restrict__ W1sl, const float* __restrict__ b1,
    float* __restrict__ P, unsigned short* __restrict__ Q)
{
    __shared__ unsigned short Ah[64 * 136];   // [m][k], pad 128->136 shorts
    __shared__ unsigned short Al[64 * 136];
    int t  = threadIdx.x;
    int r0 = blockIdx.x * 64;
    int n0 = blockIdx.y * 256;

    // --- build A (x rows) as hi/lo bf16 in LDS (packed converts) ---
    {
        int m   = (t & 15) | ((t >> 6) << 4);          // 0..63, lane-unique within wave
        int seg = (t >> 4) & 3;
        const float* xr = x + (r0 + m) * DD + seg * 32;
        #pragma unroll
        for (int it = 0; it < 4; ++it) {
            f4v v0 = *(const f4v*)(xr + it * 8);
            f4v v1 = *(const f4v*)(xr + it * 8 + 4);
            u4v hh, ll;
            #pragma unroll
            for (int pp = 0; pp < 4; ++pp) {
                f2v v;
                v[0] = (pp < 2) ? v0[pp * 2]     : v1[(pp - 2) * 2];
                v[1] = (pp < 2) ? v0[pp * 2 + 1] : v1[(pp - 2) * 2 + 1];
                unsigned hd = cvt2(v[0], v[1]);        // v_cvt_pk_bf16_f32
                f2v hf = unpk2(hd);
                f2v lo = v - hf;                       // v_pk_add_f32 (sub)
                hh[pp] = hd;
                ll[pp] = cvt2(lo[0], lo[1]);
            }
            int c = seg * 32 + it * 8;
            *(u4v*)(Ah + m * 136 + c) = hh;
            *(u4v*)(Al + m * 136 + c) = ll;
        }
    }
    __syncthreads();

    int lane = t & 63, wn = t >> 6, l15 = lane & 15, q = lane >> 4;
    f4v acc[4][4];
    #pragma unroll
    for (int mt = 0; mt < 4; ++mt)
        #pragma unroll
        for (int nt = 0; nt < 4; ++nt) acc[mt][nt] = (f4v){0.f, 0.f, 0.f, 0.f};

    #pragma unroll
    for (int kt = 0; kt < 4; ++kt) {
        s8v ah[4], al[4], bh[4], bl[4];
        #pragma unroll
        for (int mt = 0; mt < 4; ++mt) {
            int m = mt * 16 + l15;
            ah[mt] = *(const s8v*)(Ah + m * 136 + kt * 32 + q * 8);
            al[mt] = *(const s8v*)(Al + m * 136 + kt * 32 + q * 8);
        }
        #pragma unroll
        for (int nt = 0; nt < 4; ++nt) {
            int n = n0 + wn * 64 + nt * 16 + l15;      // global col 0..511
            int idx = (kt * 512 + n) * 32 + q * 8;
            bh[nt] = *(const s8v*)(W1sh + idx);
            bl[nt] = *(const s8v*)(W1sl + idx);
        }
        #pragma unroll
        for (int mt = 0; mt < 4; ++mt)
            #pragma unroll
            for (int nt = 0; nt < 4; ++nt) {
                acc[mt][nt] = __builtin_amdgcn_mfma_f32_16x16x32_bf16(ah[mt], bh[nt], acc[mt][nt], 0, 0, 0);
                acc[mt][nt] = __builtin_amdgcn_mfma_f32_16x16x32_bf16(ah[mt], bl[nt], acc[mt][nt], 0, 0, 0);
                acc[mt][nt] = __builtin_amdgcn_mfma_f32_16x16x32_bf16(al[mt], bh[nt], acc[mt][nt], 0, 0, 0);
            }
    }

    // --- epilogue: cols<256 -> P (fp32 + b1), cols>=256 -> Q (bf16) ---
    #pragma unroll
    for (int nt = 0; nt < 4; ++nt) {
        int cg = n0 + wn * 64 + nt * 16 + l15;
        if (cg < 256) {
            float bias = b1[cg];
            #pragma unroll
            for (int mt = 0; mt < 4; ++mt)
                #pragma unroll
                for (int r = 0; r < 4; ++r) {
                    int row = r0 + mt * 16 + q * 4 + r;
                    P[row * 256 + cg] = acc[mt][nt][r] + bias;
                }
        } else {
            int cq = cg - 256;
            #pragma unroll
            for (int mt = 0; mt < 4; ++mt)
                #pragma unroll
                for (int r = 0; r < 4; ++r) {
                    int row = r0 + mt * 16 + q * 4 + r;
                    Q[row * 256 + cq] = f2bf(acc[mt][nt][r]);
                }
        }
    }
}

// ---------------------------------------------------------------------------
// Kernel 2: fused main. One block = 2 nodes (M = 64 rows of h1).
//  r5 structure (== r1 perf) with ONLY the convert/VALU paths packed:
//  - phase 1: f2v packed add/max + pairwise cvt (compiler-scheduled, no asm)
//  - phase 3: f2v packed add/max/fma
//  Everything else (barriers, wbuf, LDS image, NT stream) identical to r5.
// ---------------------------------------------------------------------------
__global__ __launch_bounds__(256) void main_kernel(
    const float* __restrict__ P, const unsigned short* __restrict__ Q,
    const unsigned short* __restrict__ W2s,
    const float* __restrict__ b2, const float* __restrict__ W3,
    const int* __restrict__ nbrs, const float* __restrict__ t_arr,
    const float* __restrict__ e_hat, const float* __restrict__ b3p,
    const float* __restrict__ bscal, float* __restrict__ out)
{
    __shared__ unsigned short A[64 * 264];   // h1 bf16 [m][k] pad 256->264; reused as 32KB row image
    __shared__ float mlpbuf[64][4];          // per-row partial mlp by wave
    __shared__ float wbuf_w[2][32];          // per-node scatter values
    __shared__ int   wbuf_j[2][32];          // per-node scatter columns (-1 = skip)
    int t = threadIdx.x;
    int node0 = blockIdx.x * 2;
    float* PW = out + NN;                    // pairwise base

    // --- phase 1: build h1 = bf16(relu(P[g] + Q[j])) into LDS, packed ---
    {
        int m   = (t & 15) | ((t >> 6) << 4);     // 0..63
        int seg = (t >> 4) & 3;
        int g = node0 + (m >> 5);
        int j = nbrs[g * 33 + 1 + (m & 31)];      // only dependent load
        const float* Pr = P + g * 256 + seg * 64; // cur == g
        const unsigned short* Qr = Q + j * 256 + seg * 64;

        #pragma unroll
        for (int half = 0; half < 2; ++half) {
            // stage 12 independent loads, then packed convert
            f4v p0[4], p1[4];
            u4v qv[4];
            #pragma unroll
            for (int it = 0; it < 4; ++it) {
                int itg = half * 4 + it;
                p0[it] = *(const f4v*)(Pr + itg * 8);
                p1[it] = *(const f4v*)(Pr + itg * 8 + 4);
                qv[it] = *(const u4v*)(Qr + itg * 8);
            }
            #pragma unroll
            for (int it = 0; it < 4; ++it) {
                int itg = half * 4 + it;
                u4v hv;
                #pragma unroll
                for (int pp = 0; pp < 4; ++pp) {
                    f2v pv;
                    pv[0] = (pp < 2) ? p0[it][pp * 2]     : p1[it][(pp - 2) * 2];
                    pv[1] = (pp < 2) ? p0[it][pp * 2 + 1] : p1[it][(pp - 2) * 2 + 1];
                    f2v qf = unpk2(qv[it][pp]);
                    f2v s = pv + qf;                           // v_pk_add_f32
                    s = __builtin_elementwise_max(s, (f2v){0.f, 0.f}); // v_pk_max_f32
                    hv[pp] = cvt2(s[0], s[1]);                 // v_cvt_pk_bf16_f32
                }
                *(u4v*)(A + m * 264 + seg * 64 + itg * 8) = hv;
            }
        }
    }
    __syncthreads();

    // --- phase 2: K-loop, no barriers. B direct from L2. ---
    int lane = t & 63, wn = t >> 6, l15 = lane & 15, q = lane >> 4;
    f4v acc[4][4];
    #pragma unroll
    for (int mt = 0; mt < 4; ++mt)
        #pragma unroll
        for (int nt = 0; nt < 4; ++nt) acc[mt][nt] = (f4v){0.f, 0.f, 0.f, 0.f};

    #pragma unroll
    for (int kt = 0; kt < 8; ++kt) {
        s8v a[4], b[4];
        #pragma unroll
        for (int mt = 0; mt < 4; ++mt)
            a[mt] = *(const s8v*)(A + (mt * 16 + l15) * 264 + kt * 32 + q * 8);
        #pragma unroll
        for (int nt = 0; nt < 4; ++nt) {
            int n = wn * 64 + nt * 16 + l15;
            b[nt] = *(const s8v*)(W2s + (kt * 256 + n) * 32 + q * 8);
        }
        #pragma unroll
        for (int mt = 0; mt < 4; ++mt)
            #pragma unroll
            for (int nt = 0; nt < 4; ++nt)
                acc[mt][nt] = __builtin_amdgcn_mfma_f32_16x16x32_bf16(a[mt], b[nt], acc[mt][nt], 0, 0, 0);
    }

    // --- phase 3: mlp partials = sum_c relu(h2+b2)*W3, packed pairs ---
    f2v p2[4][2];
    #pragma unroll
    for (int mt = 0; mt < 4; ++mt) {
        p2[mt][0] = (f2v){0.f, 0.f};
        p2[mt][1] = (f2v){0.f, 0.f};
    }
    #pragma unroll
    for (int nt = 0; nt < 4; ++nt) {
        int c = wn * 64 + nt * 16 + l15;
        float bb = b2[c], w3 = W3[c];
        f2v bb2 = (f2v){bb, bb};
        f2v w32 = (f2v){w3, w3};
        #pragma unroll
        for (int mt = 0; mt < 4; ++mt) {
            f2v lo = (f2v){acc[mt][nt][0], acc[mt][nt][1]};
            f2v hi = (f2v){acc[mt][nt][2], acc[mt][nt][3]};
            lo = lo + bb2;                                     // v_pk_add_f32
            hi = hi + bb2;
            lo = __builtin_elementwise_max(lo, (f2v){0.f, 0.f});
            hi = __builtin_elementwise_max(hi, (f2v){0.f, 0.f});
            p2[mt][0] = p2[mt][0] + lo * w32;                  // v_pk_fma_f32
            p2[mt][1] = p2[mt][1] + hi * w32;
        }
    }
    #pragma unroll
    for (int off = 1; off < 16; off <<= 1)
        #pragma unroll
        for (int mt = 0; mt < 4; ++mt)
            #pragma unroll
            for (int rr = 0; rr < 2; ++rr)
                #pragma unroll
                for (int cc = 0; cc < 2; ++cc)
                    p2[mt][rr][cc] += __shfl_xor(p2[mt][rr][cc], off, 64);
    if (l15 == 0) {
        #pragma unroll
        for (int mt = 0; mt < 4; ++mt)
            #pragma unroll
            for (int r = 0; r < 4; ++r)
                mlpbuf[mt * 16 + q * 4 + r][wn] = p2[mt][r >> 1][r & 1];
    }
    __syncthreads();   // mlpbuf ready; A free (K-loop LDS reads all complete)

    // --- phase 4 (waves 0-1): softmax, Y_pred, scatter list
    //     (waves 2-3): zero the 32KB row image in parallel ---
    float* img = (float*)A;
    if (t < 128) {
        int node = t >> 6;
        int k = t & 63;
        if (k < 32) {
            int g = node0 + node;
            int m = node * 32 + k;
            float mlp = mlpbuf[m][0] + mlpbuf[m][1] + mlpbuf[m][2] + mlpbuf[m][3] + b3p[0];
            float aabs = bscal[0] * fabsf(mlp);
            float amax = aabs;
            #pragma unroll
            for (int off = 1; off < 32; off <<= 1)
                amax = fmaxf(amax, __shfl_xor(amax, off, 64));
            float e = __expf(aabs - amax);
            float s = e;
            #pragma unroll
            for (int off = 1; off < 32; off <<= 1)
                s += __shfl_xor(s, off, 64);
            float w = mlp * (e / s);

            int j = nbrs[g * 33 + 1 + k];
            float prop = t_arr[j] - e_hat[j];
            float yp = prop * w;
            #pragma unroll
            for (int off = 1; off < 32; off <<= 1)
                yp += __shfl_xor(yp, off, 64);
            if (k == 0) out[g] = yp;

            // numpy last-write-wins dedup; skip diagonal (cur == g)
            bool write = (j != g);
            for (int kk = 0; kk < 32; ++kk) {
                int jv = __shfl(j, kk, 64);
                if (kk > k && jv == j) write = false;
            }
            wbuf_w[node][k] = w;
            wbuf_j[node][k] = write ? j : -1;
        }
    } else {
        int tt = t - 128;                     // 0..127, 64 floats each
        f4v z = (f4v){0.f, 0.f, 0.f, 0.f};
        #pragma unroll
        for (int i = 0; i < 16; ++i)
            *(f4v*)(img + tt * 4 + i * 512) = z;
    }
    __syncthreads();                          // wbuf + zeros visible

    // --- phase 5: stream row 0 (rezeroing image for row 1), then row 1 ---
    if (t < 32) {
        int j = wbuf_j[0][t];
        if (j >= 0) img[j] = wbuf_w[0][t];
    }
    __syncthreads();
    {
        float* dst = PW + (long)node0 * NN;   // cur == node0
        f4v z = (f4v){0.f, 0.f, 0.f, 0.f};
        #pragma unroll
        for (int i = 0; i < 8; ++i) {
            f4v v = *(const f4v*)(img + t * 4 + i * 1024);
            *(f4v*)(img + t * 4 + i * 1024) = z;   // same-thread rezero (wave-ordered)
            __builtin_nontemporal_store(v, (f4v*)(dst + t * 4 + i * 1024));
        }
    }
    __syncthreads();
    if (t < 32) {
        int j = wbuf_j[1][t];
        if (j >= 0) img[j] = wbuf_w[1][t];
    }
    __syncthreads();
    {
        float* dst = PW + (long)(node0 + 1) * NN;
        #pragma unroll
        for (int i = 0; i < 8; ++i) {
            f4v v = *(const f4v*)(img + t * 4 + i * 1024);
            __builtin_nontemporal_store(v, (f4v*)(dst + t * 4 + i * 1024));
        }
    }
}

// ---------------------------------------------------------------------------
extern "C" void kernel_launch(void* const* d_in, const int* in_sizes, int n_in,
                              void* d_out, int out_size, void* d_ws, size_t ws_size,
                              hipStream_t stream) {
    const float* x     = (const float*)d_in[0];
    const int*   nbrs  = (const int*)d_in[1];
    const float* t     = (const float*)d_in[2];
    const float* e_hat = (const float*)d_in[3];
    const float* W1    = (const float*)d_in[4];
    const float* b1    = (const float*)d_in[5];
    const float* W2    = (const float*)d_in[6];
    const float* b2    = (const float*)d_in[7];
    const float* W3    = (const float*)d_in[8];
    const float* b3    = (const float*)d_in[9];
    const float* b     = (const float*)d_in[10];

    char* ws = (char*)d_ws;
    float*          P     = (float*)ws;                              // 8 MB
    unsigned short* Q     = (unsigned short*)(ws + 8388608);         // 4 MB
    unsigned short* W1sh  = (unsigned short*)(ws + 12582912);        // 128 KB
    unsigned short* W1sl  = (unsigned short*)(ws + 12713984);        // 128 KB
    unsigned short* W2s   = (unsigned short*)(ws + 12845056);        // 128 KB

    prep_kernel<<<512, 256, 0, stream>>>(W1, W2, W1sh, W1sl, W2s);
    pq_kernel<<<dim3(128, 2), 256, 0, stream>>>(x, W1sh, W1sl, b1, P, Q);
    main_kernel<<<4096, 256, 0, stream>>>(P, Q, W2s, b2, W3, nbrs, t, e_hat,
                                          b3, b, (float*)d_out);
}